// Round 4
// baseline (525.567 us; speedup 1.0000x reference)
//
#include <hip/hip_runtime.h>

#define HH 512
#define LL 2048
#define NN 64
#define TT 128          // chunk length (= 2^7, Ab^128 from squaring chain)
#define CC 16           // number of chunks, CC*TT == LL
#define LDA 68          // padded LDS leading dim

__device__ __forceinline__ float2 cmul(float2 a, float2 b) {
    return make_float2(a.x * b.x - a.y * b.y, a.x * b.y + a.y * b.x);
}
__device__ __forceinline__ float2 crecip(float2 a) {
    float id = 1.0f / (a.x * a.x + a.y * a.y);
    return make_float2(a.x * id, -a.y * id);
}

template <int CTRL>
__device__ __forceinline__ float dpp_mov(float x) {
    return __int_as_float(__builtin_amdgcn_update_dpp(
        0, __float_as_int(x), CTRL, 0xf, 0xf, true));
}
__device__ __forceinline__ float wave_sum_bcast(float x) {
    x += dpp_mov<0x111>(x);
    x += dpp_mov<0x112>(x);
    x += dpp_mov<0x114>(x);
    x += dpp_mov<0x118>(x);
    x += dpp_mov<0x142>(x);
    x += dpp_mov<0x143>(x);
    return __int_as_float(__builtin_amdgcn_readlane(__float_as_int(x), 63));
}
__device__ __forceinline__ float wave_max_bcast(float x) {
    x = fmaxf(x, dpp_mov<0x111>(x));
    x = fmaxf(x, dpp_mov<0x112>(x));
    x = fmaxf(x, dpp_mov<0x114>(x));
    x = fmaxf(x, dpp_mov<0x118>(x));
    x = fmaxf(x, dpp_mov<0x142>(x));
    x = fmaxf(x, dpp_mov<0x143>(x));
    return __int_as_float(__builtin_amdgcn_readlane(__float_as_int(x), 63));
}
__device__ __forceinline__ float rlane(float x, int i) {
    return __int_as_float(__builtin_amdgcn_readlane(__float_as_int(x), i));
}

// Per head: build Ab = diag(da) - DP (x) t, square 11x in LDS.
// 256 threads = 2 k-halves x (8-row x 4-col tiles): split-k with in-place
// LDS reduction (partials stored into the destination slots between barriers).
// Stash Ab^128 (it==6, transposed, coalesced) for combine; then Gauss-Jordan
// solve (I - Ab^L)[Bt,x0t]=[Bb,x0].
extern "C" __global__ void __launch_bounds__(256)
k_precompute(const float* __restrict__ x0_re, const float* __restrict__ x0_im,
             const float* __restrict__ Lre, const float* __restrict__ Lim,
             const float* __restrict__ Pre, const float* __restrict__ Pim,
             const float* __restrict__ Bre, const float* __restrict__ Bim,
             const float* __restrict__ logstep,
             float2* __restrict__ wda, float2* __restrict__ wDP,
             float2* __restrict__ wt, float2* __restrict__ wBt,
             float2* __restrict__ wx0, float2* __restrict__ wM) {
    __shared__ __align__(16) float Ar[NN * LDA];
    __shared__ __align__(16) float Ai[NN * LDA];
    __shared__ float2 sda[NN], sDP[NN], st[NN], srhs[NN], srhs2[NN], sf[NN];

    const int h = blockIdx.x;
    const int tid = threadIdx.x;

    if (tid < NN) {
        const int n = tid;
        float step = expf(logstep[h]);
        float as = 2.0f / step;
        float lr = fminf(Lre[h * NN + n], -1e-4f);
        float li = Lim[h * NN + n];
        float2 a = make_float2(as + lr, li);
        float2 Dn = crecip(make_float2(as - lr, -li));
        float2 P = make_float2(Pre[h * NN + n], Pim[h * NN + n]);
        float2 Bv = make_float2(Bre[h * NN + n], Bim[h * NN + n]);
        float2 cP = make_float2(P.x, -P.y);
        float p2 = P.x * P.x + P.y * P.y;
        float2 rt = cmul(cmul(cP, Dn), Bv);
        float2 e = make_float2(wave_sum_bcast(Dn.x * p2), wave_sum_bcast(Dn.y * p2));
        float2 rv = make_float2(wave_sum_bcast(rt.x), wave_sum_bcast(rt.y));
        float2 cc = crecip(make_float2(1.0f + e.x, e.y));
        float2 da = cmul(Dn, a);
        float2 DPv = cmul(Dn, P);
        float2 tmp = cmul(cc, make_float2(da.x - e.x, da.y - e.y));
        float2 tv = cmul(cP, make_float2(1.0f + tmp.x, tmp.y));
        float2 crv = cmul(cc, rv);
        float2 cd = cmul(crv, DPv);
        float2 db = cmul(Dn, Bv);
        float2 bb = make_float2(2.0f * (db.x - cd.x), 2.0f * (db.y - cd.y));
        sda[n] = da; sDP[n] = DPv; st[n] = tv; srhs[n] = bb;
        srhs2[n] = make_float2(x0_re[n * HH + h], x0_im[n * HH + h]);
        wda[h * NN + n] = da; wDP[h * NN + n] = DPv; wt[h * NN + n] = tv;
    }
    __syncthreads();

    for (int idx = tid; idx < NN * NN; idx += 256) {
        int i = idx >> 6, j = idx & 63;
        float2 v = cmul(sDP[i], st[j]);
        float mr = -v.x, mi = -v.y;
        if (i == j) { mr += sda[i].x; mi += sda[i].y; }
        Ar[i * LDA + j] = mr; Ai[i * LDA + j] = mi;
    }
    __syncthreads();

    // 11 in-place squarings: split-k (2 halves), 8x4 tile per thread.
    const int kh = tid >> 7;            // k-half: 0 or 1
    const int lt = tid & 127;
    const int i0 = (lt >> 4) << 3;      // 8-row tile
    const int j0 = (lt & 15) << 2;      // 4-col tile
    const int kbase = kh << 5;          // 0 or 32
    for (int it = 0; it < 11; ++it) {
        float acr[8][4] = {}, aci[8][4] = {};
        for (int kk = kbase; kk < kbase + 32; kk += 4) {
            float4 a_r[8], a_i[8], b_r4[4], b_i4[4];
            #pragma unroll
            for (int r = 0; r < 8; ++r) {
                a_r[r] = *(const float4*)&Ar[(i0 + r) * LDA + kk];
                a_i[r] = *(const float4*)&Ai[(i0 + r) * LDA + kk];
            }
            #pragma unroll
            for (int q = 0; q < 4; ++q) {
                b_r4[q] = *(const float4*)&Ar[(kk + q) * LDA + j0];
                b_i4[q] = *(const float4*)&Ai[(kk + q) * LDA + j0];
            }
            #pragma unroll
            for (int r = 0; r < 8; ++r) {
                const float* arp = (const float*)&a_r[r];
                const float* aip = (const float*)&a_i[r];
                #pragma unroll
                for (int q = 0; q < 4; ++q) {
                    const float axr = arp[q], axi = aip[q];
                    const float* brp = (const float*)&b_r4[q];
                    const float* bip = (const float*)&b_i4[q];
                    #pragma unroll
                    for (int c = 0; c < 4; ++c) {
                        acr[r][c] += axr * brp[c] - axi * bip[c];
                        aci[r][c] += axr * bip[c] + axi * brp[c];
                    }
                }
            }
        }
        __syncthreads();   // all reads done
        if (kh == 1) {
            #pragma unroll
            for (int r = 0; r < 8; ++r) {
                *(float4*)&Ar[(i0 + r) * LDA + j0] = *(float4*)acr[r];
                *(float4*)&Ai[(i0 + r) * LDA + j0] = *(float4*)aci[r];
            }
        }
        __syncthreads();   // kh1 partials visible
        if (kh == 0) {
            #pragma unroll
            for (int r = 0; r < 8; ++r) {
                float4 pr = *(const float4*)&Ar[(i0 + r) * LDA + j0];
                float4 pi = *(const float4*)&Ai[(i0 + r) * LDA + j0];
                acr[r][0] += pr.x; acr[r][1] += pr.y;
                acr[r][2] += pr.z; acr[r][3] += pr.w;
                aci[r][0] += pi.x; aci[r][1] += pi.y;
                aci[r][2] += pi.z; aci[r][3] += pi.w;
                *(float4*)&Ar[(i0 + r) * LDA + j0] = *(float4*)acr[r];
                *(float4*)&Ai[(i0 + r) * LDA + j0] = *(float4*)aci[r];
            }
        }
        __syncthreads();
        if (it == 6) {
            // stash M = Ab^128 transposed (wM[h][j][i] = M[i][j]), coalesced
            for (int idx = tid; idx < NN * NN; idx += 256) {
                int j = idx >> 6, i = idx & 63;
                wM[h * NN * NN + idx] =
                    make_float2(Ar[i * LDA + j], Ai[i * LDA + j]);
            }
        }
    }

    // V = I - Ab^L
    for (int idx = tid; idx < NN * NN; idx += 256) {
        int i = idx >> 6, j = idx & 63;
        float mr = Ar[i * LDA + j], mi = Ai[i * LDA + j];
        Ar[i * LDA + j] = (i == j ? 1.0f : 0.0f) - mr;
        Ai[i * LDA + j] = -mi;
    }
    __syncthreads();

    // Gauss-Jordan with partial pivoting, 2 RHS
    for (int col = 0; col < NN; ++col) {
        if (tid < 64) {
            const int lane = tid;
            float vr = Ar[lane * LDA + col], vi = Ai[lane * LDA + col];
            float mag = (lane >= col) ? (vr * vr + vi * vi) : 0.0f;
            float vmax = wave_max_bcast(mag);
            unsigned long long ball = __ballot((mag == vmax) && (lane >= col));
            int p = (int)__builtin_ctzll(ball);
            if (p != col) {
                float t1r = Ar[col * LDA + lane], t1i = Ai[col * LDA + lane];
                float t2r = Ar[p * LDA + lane], t2i = Ai[p * LDA + lane];
                Ar[col * LDA + lane] = t2r; Ai[col * LDA + lane] = t2i;
                Ar[p * LDA + lane] = t1r;   Ai[p * LDA + lane] = t1i;
                if (lane == 0) { float2 q = srhs[col]; srhs[col] = srhs[p]; srhs[p] = q; }
                if (lane == 1) { float2 q = srhs2[col]; srhs2[col] = srhs2[p]; srhs2[p] = q; }
            }
        }
        __syncthreads();
        if (tid < 64) {
            const int lane = tid;
            sf[lane] = make_float2(Ar[lane * LDA + col], Ai[lane * LDA + col]);
            float2 ip = crecip(make_float2(Ar[col * LDA + col], Ai[col * LDA + col]));
            float rr = Ar[col * LDA + lane], ri = Ai[col * LDA + lane];
            Ar[col * LDA + lane] = rr * ip.x - ri * ip.y;
            Ai[col * LDA + lane] = rr * ip.y + ri * ip.x;
            if (lane == 0) srhs[col] = cmul(srhs[col], ip);
            if (lane == 1) srhs2[col] = cmul(srhs2[col], ip);
        }
        __syncthreads();
        {
            const int i = tid >> 2, jb = (tid & 3) * 16;
            if (i != col) {
                float2 f = sf[i];
                #pragma unroll
                for (int jj = 0; jj < 16; ++jj) {
                    int j = jb + jj;
                    float pr = Ar[col * LDA + j], pi = Ai[col * LDA + j];
                    float cr = Ar[i * LDA + j], ci = Ai[i * LDA + j];
                    cr -= f.x * pr - f.y * pi;
                    ci -= f.x * pi + f.y * pr;
                    Ar[i * LDA + j] = cr; Ai[i * LDA + j] = ci;
                }
                if ((tid & 3) == 0) {
                    float2 pr = srhs[col]; float2 cu = srhs[i];
                    cu.x -= f.x * pr.x - f.y * pr.y;
                    cu.y -= f.x * pr.y + f.y * pr.x;
                    srhs[i] = cu;
                    pr = srhs2[col]; cu = srhs2[i];
                    cu.x -= f.x * pr.x - f.y * pr.y;
                    cu.y -= f.x * pr.y + f.y * pr.x;
                    srhs2[i] = cu;
                }
            }
        }
        __syncthreads();
    }
    if (tid < NN) {
        wBt[h * NN + tid] = srhs[tid];
        wx0[h * NN + tid] = srhs2[tid];
    }
}

// m=4 blocked chunk scan, one wave per (head, chunk); 4 waves per block
// (no barriers — waves are independent) to raise waves/SIMD.
template <int EMIT>
__device__ __forceinline__ void scan_core(
    int h, int c, int lane,
    const float* __restrict__ u, const float* __restrict__ Cmat,
    const float* __restrict__ Dvec,
    const float2* __restrict__ wda, const float2* __restrict__ wDP,
    const float2* __restrict__ wt, const float2* __restrict__ wBt,
    const float2* __restrict__ wXs, float2* __restrict__ wPend,
    float* __restrict__ out) {
    const float2 da = wda[h * NN + lane];
    const float2 DP = wDP[h * NN + lane];
    const float2 tt = wt[h * NN + lane];
    const float2 Bt = wBt[h * NN + lane];

    float dapr[5], dapi[5];
    dapr[0] = 1.0f; dapi[0] = 0.0f;
    #pragma unroll
    for (int j = 1; j <= 4; ++j) {
        dapr[j] = dapr[j-1] * da.x - dapi[j-1] * da.y;
        dapi[j] = dapr[j-1] * da.y + dapi[j-1] * da.x;
    }
    float tdar[4], tdai[4], edpr[4], edpi[4];
    #pragma unroll
    for (int j = 0; j < 4; ++j) {
        tdar[j] = tt.x * dapr[j] - tt.y * dapi[j];
        tdai[j] = tt.x * dapi[j] + tt.y * dapr[j];
        edpr[j] = DP.x * dapr[j] - DP.y * dapi[j];
        edpi[j] = DP.x * dapi[j] + DP.y * dapr[j];
    }
    float taur[4], taui[4];
    #pragma unroll
    for (int j = 0; j < 4; ++j) {
        taur[j] = wave_sum_bcast(tdar[j] * DP.x - tdai[j] * DP.y);
        taui[j] = wave_sum_bcast(tdar[j] * DP.y + tdai[j] * DP.x);
    }
    float thr[4], thi[4];
    thr[0] = 1.0f; thi[0] = 0.0f;
    thr[1] = -taur[0]; thi[1] = -taui[0];
    thr[2] = -(taur[0]*thr[1] - taui[0]*thi[1] + taur[1]);
    thi[2] = -(taur[0]*thi[1] + taui[0]*thr[1] + taui[1]);
    thr[3] = -(taur[0]*thr[2] - taui[0]*thi[2] + taur[1]*thr[1] - taui[1]*thi[1] + taur[2]);
    thi[3] = -(taur[0]*thi[2] + taui[0]*thr[2] + taur[1]*thi[1] + taui[1]*thr[1] + taui[2]);
    float fr[4], fi[4];
    #pragma unroll
    for (int j = 0; j < 4; ++j) {
        float ar = 0.0f, ai = 0.0f;
        #pragma unroll
        for (int i = 0; i < 4; ++i) {
            int d = 3 - j - i;
            if (d >= 0) {
                ar += edpr[i]*thr[d] - edpi[i]*thi[d];
                ai += edpr[i]*thi[d] + edpi[i]*thr[d];
            }
        }
        fr[j] = ar; fi[j] = ai;
    }
    float Gr[4], Gi[4];
    Gr[0] = Bt.x; Gi[0] = Bt.y;
    #pragma unroll
    for (int k = 0; k < 3; ++k) {
        float gdr = wave_sum_bcast(tt.x * Gr[k] - tt.y * Gi[k]);
        float gdi = wave_sum_bcast(tt.x * Gi[k] + tt.y * Gr[k]);
        Gr[k+1] = da.x * Gr[k] - da.y * Gi[k] - (DP.x * gdr - DP.y * gdi);
        Gi[k+1] = da.x * Gi[k] + da.y * Gr[k] - (DP.x * gdi + DP.y * gdr);
    }
    const float damr = dapr[4], dami = dapi[4];

    float cCr = 0.0f, cCi = 0.0f, Dh = 0.0f;
    float csr[4], csi[4], psir[4], psii[4], Kr4[4];
    if (EMIT) {
        cCr = Cmat[h * NN * 2 + lane * 2 + 0];
        cCi = -Cmat[h * NN * 2 + lane * 2 + 1];
        Dh = Dvec[h];
        #pragma unroll
        for (int j = 0; j < 4; ++j) {
            csr[j] = cCr * dapr[j+1] - cCi * dapi[j+1];
            csi[j] = cCr * dapi[j+1] + cCi * dapr[j+1];
        }
        float kapr[4], kapi[4];
        const float cdpr = cCr * DP.x - cCi * DP.y;
        const float cdpi = cCr * DP.y + cCi * DP.x;
        #pragma unroll
        for (int j = 0; j < 4; ++j) {
            kapr[j] = wave_sum_bcast(cdpr * dapr[j] - cdpi * dapi[j]);
            kapi[j] = wave_sum_bcast(cdpr * dapi[j] + cdpi * dapr[j]);
        }
        #pragma unroll
        for (int cc2 = 0; cc2 < 4; ++cc2) {
            float ar = 0.0f, ai = 0.0f;
            #pragma unroll
            for (int i = 0; i < 4; ++i) {
                if (i <= cc2) {
                    int d = cc2 - i;
                    ar += kapr[i]*thr[d] - kapi[i]*thi[d];
                    ai += kapr[i]*thi[d] + kapi[i]*thr[d];
                }
            }
            psir[cc2] = ar; psii[cc2] = ai;
        }
        #pragma unroll
        for (int k = 0; k < 4; ++k)
            Kr4[k] = wave_sum_bcast(cCr * Gr[k] - cCi * Gi[k]);
    }

    float xr, xi;
    if (EMIT) {
        float2 xs = wXs[(h * CC + c) * NN + lane];
        xr = xs.x; xi = xs.y;
    } else {
        xr = 0.0f; xi = 0.0f;
    }

    const int NCH = EMIT ? 12 : 8;
    const int base = c * TT;
    for (int t0 = base; t0 < base + TT; t0 += 64) {
        const float uv = u[(t0 + lane) * HH + h];
        float yout = 0.0f;
        #pragma unroll 2
        for (int b = 0; b < 16; ++b) {
            const int lb = b << 2;
            const float us0 = rlane(uv, lb);
            const float us1 = rlane(uv, lb + 1);
            const float us2 = rlane(uv, lb + 2);
            const float us3 = rlane(uv, lb + 3);
            float ch[12];
            #pragma unroll
            for (int j = 0; j < 4; ++j) {
                ch[j]     = tdar[j] * xr - tdai[j] * xi;
                ch[4 + j] = tdar[j] * xi + tdai[j] * xr;
            }
            if (EMIT) {
                #pragma unroll
                for (int j = 0; j < 4; ++j)
                    ch[8 + j] = csr[j] * xr - csi[j] * xi;
            }
            #pragma unroll
            for (int c2 = 0; c2 < NCH; ++c2) ch[c2] += dpp_mov<0x111>(ch[c2]);
            #pragma unroll
            for (int c2 = 0; c2 < NCH; ++c2) ch[c2] += dpp_mov<0x112>(ch[c2]);
            #pragma unroll
            for (int c2 = 0; c2 < NCH; ++c2) ch[c2] += dpp_mov<0x114>(ch[c2]);
            #pragma unroll
            for (int c2 = 0; c2 < NCH; ++c2) ch[c2] += dpp_mov<0x118>(ch[c2]);
            #pragma unroll
            for (int c2 = 0; c2 < NCH; ++c2) ch[c2] += dpp_mov<0x142>(ch[c2]);
            #pragma unroll
            for (int c2 = 0; c2 < NCH; ++c2) ch[c2] += dpp_mov<0x143>(ch[c2]);
            float RR[4], RI[4];
            #pragma unroll
            for (int j = 0; j < 4; ++j) {
                RR[j] = rlane(ch[j], 63);
                RI[j] = rlane(ch[4 + j], 63);
            }
            if (EMIT) {
                float SG[4];
                #pragma unroll
                for (int j = 0; j < 4; ++j) SG[j] = rlane(ch[8 + j], 63);
                const float y0 = SG[0] - (psir[0]*RR[0] - psii[0]*RI[0]) + Kr4[0]*us0;
                const float y1 = SG[1] - (psir[1]*RR[0] - psii[1]*RI[0])
                                       - (psir[0]*RR[1] - psii[0]*RI[1])
                               + Kr4[1]*us0 + Kr4[0]*us1;
                const float y2 = SG[2] - (psir[2]*RR[0] - psii[2]*RI[0])
                                       - (psir[1]*RR[1] - psii[1]*RI[1])
                                       - (psir[0]*RR[2] - psii[0]*RI[2])
                               + Kr4[2]*us0 + Kr4[1]*us1 + Kr4[0]*us2;
                const float y3 = SG[3] - (psir[3]*RR[0] - psii[3]*RI[0])
                                       - (psir[2]*RR[1] - psii[2]*RI[1])
                                       - (psir[1]*RR[2] - psii[1]*RI[2])
                                       - (psir[0]*RR[3] - psii[0]*RI[3])
                               + Kr4[3]*us0 + Kr4[2]*us1 + Kr4[1]*us2 + Kr4[0]*us3;
                if (lane == lb)     yout = y0;
                if (lane == lb + 1) yout = y1;
                if (lane == lb + 2) yout = y2;
                if (lane == lb + 3) yout = y3;
            }
            float nxr = damr * xr - dami * xi;
            float nxi = damr * xi + dami * xr;
            #pragma unroll
            for (int j = 0; j < 4; ++j) {
                nxr -= fr[j] * RR[j] - fi[j] * RI[j];
                nxi -= fr[j] * RI[j] + fi[j] * RR[j];
            }
            nxr += Gr[3]*us0 + Gr[2]*us1 + Gr[1]*us2 + Gr[0]*us3;
            nxi += Gi[3]*us0 + Gi[2]*us1 + Gi[1]*us2 + Gi[0]*us3;
            xr = nxr; xi = nxi;
        }
        if (EMIT) out[(t0 + lane) * HH + h] = yout + Dh * uv;
    }
    if (!EMIT) wPend[(h * CC + c) * NN + lane] = make_float2(xr, xi);
}

extern "C" __global__ void __launch_bounds__(256)
k_scanA(const float* __restrict__ u,
        const float2* __restrict__ wda, const float2* __restrict__ wDP,
        const float2* __restrict__ wt, const float2* __restrict__ wBt,
        float2* __restrict__ wPend) {
    const int c = blockIdx.y * 4 + (threadIdx.x >> 6);
    if (c >= CC - 1) return;   // chunks 0..14 (whole-wave exit, no barriers)
    scan_core<0>(blockIdx.x, c, threadIdx.x & 63,
                 u, nullptr, nullptr, wda, wDP, wt, wBt, nullptr, wPend, nullptr);
}

extern "C" __global__ void __launch_bounds__(256)
k_scanC(const float* __restrict__ u, const float* __restrict__ Cmat,
        const float* __restrict__ Dvec,
        const float2* __restrict__ wda, const float2* __restrict__ wDP,
        const float2* __restrict__ wt, const float2* __restrict__ wBt,
        const float2* __restrict__ wXs, float* __restrict__ out) {
    const int c = blockIdx.y * 4 + (threadIdx.x >> 6);
    scan_core<1>(blockIdx.x, c, threadIdx.x & 63,
                 u, Cmat, Dvec, wda, wDP, wt, wBt, wXs, nullptr, out);
}

// Sequential chunk-boundary combine: x_start(c) = M x_start(c-1) + p_end(c-1),
// M = Ab^128 (stored transposed). One wave per head.
extern "C" __global__ void __launch_bounds__(64)
k_combine(const float2* __restrict__ wM, const float2* __restrict__ wPend,
          const float2* __restrict__ wx0, float2* __restrict__ wXs) {
    __shared__ float2 sM[NN * NN];   // sM[j*64+i] = M[i][j]
    const int h = blockIdx.x;
    const int lane = threadIdx.x;
    for (int idx = lane; idx < NN * NN; idx += 64)
        sM[idx] = wM[h * NN * NN + idx];
    __syncthreads();
    float2 x = wx0[h * NN + lane];
    float xr = x.x, xi = x.y;
    wXs[(h * CC + 0) * NN + lane] = x;
    for (int c = 1; c < CC; ++c) {
        float nr = 0.0f, ni = 0.0f;
        #pragma unroll 4
        for (int j = 0; j < NN; ++j) {
            const float xjr = rlane(xr, j);
            const float xji = rlane(xi, j);
            const float2 m = sM[j * NN + lane];
            nr += m.x * xjr - m.y * xji;
            ni += m.x * xji + m.y * xjr;
        }
        const float2 pe = wPend[(h * CC + (c - 1)) * NN + lane];
        xr = nr + pe.x; xi = ni + pe.y;
        wXs[(h * CC + c) * NN + lane] = make_float2(xr, xi);
    }
}

extern "C" void kernel_launch(void* const* d_in, const int* in_sizes, int n_in,
                              void* d_out, int out_size, void* d_ws, size_t ws_size,
                              hipStream_t stream) {
    const float* u    = (const float*)d_in[0];
    const float* x0re = (const float*)d_in[1];
    const float* x0im = (const float*)d_in[2];
    const float* Lre  = (const float*)d_in[3];
    const float* Lim  = (const float*)d_in[4];
    const float* Pre  = (const float*)d_in[5];
    const float* Pim  = (const float*)d_in[6];
    const float* Bre  = (const float*)d_in[7];
    const float* Bim  = (const float*)d_in[8];
    const float* C    = (const float*)d_in[9];
    const float* Dv   = (const float*)d_in[10];
    const float* lst  = (const float*)d_in[11];

    float2* wda   = (float2*)d_ws;
    float2* wDP   = wda + HH * NN;
    float2* wt    = wDP + HH * NN;
    float2* wBt   = wt + HH * NN;
    float2* wx0   = wBt + HH * NN;
    float2* wM    = wx0 + HH * NN;            // 512 * 4096 float2 = 16.8 MB
    float2* wPend = wM + HH * NN * NN;        // 512 * 16 * 64 float2
    float2* wXs   = wPend + HH * CC * NN;     // 512 * 16 * 64 float2
    float* out = (float*)d_out;

    hipLaunchKernelGGL(k_precompute, dim3(HH), dim3(256), 0, stream,
                       x0re, x0im, Lre, Lim, Pre, Pim, Bre, Bim, lst,
                       wda, wDP, wt, wBt, wx0, wM);
    hipLaunchKernelGGL(k_scanA, dim3(HH, 4), dim3(256), 0, stream,
                       u, wda, wDP, wt, wBt, wPend);
    hipLaunchKernelGGL(k_combine, dim3(HH), dim3(64), 0, stream,
                       wM, wPend, wx0, wXs);
    hipLaunchKernelGGL(k_scanC, dim3(HH, 4), dim3(256), 0, stream,
                       u, C, Dv, wda, wDP, wt, wBt, wXs, out);
}

// Round 5
// 440.628 us; speedup vs baseline: 1.1928x; 1.1928x over previous
//
#include <hip/hip_runtime.h>

#define HH 512
#define LL 2048
#define NN 64
#define TT 64           // chunk length (Ab^64 = squaring chain it==5)
#define CC 32           // chunks, CC*TT == LL
#define LDA 68          // padded LDS leading dim (precompute)

__device__ __forceinline__ float2 cmul(float2 a, float2 b) {
    return make_float2(a.x * b.x - a.y * b.y, a.x * b.y + a.y * b.x);
}
__device__ __forceinline__ float2 crecip(float2 a) {
    float id = 1.0f / (a.x * a.x + a.y * a.y);
    return make_float2(a.x * id, -a.y * id);
}

template <int CTRL>
__device__ __forceinline__ float dpp_mov(float x) {
    return __int_as_float(__builtin_amdgcn_update_dpp(
        0, __float_as_int(x), CTRL, 0xf, 0xf, true));
}
__device__ __forceinline__ float wave_sum_bcast(float x) {
    x += dpp_mov<0x111>(x);
    x += dpp_mov<0x112>(x);
    x += dpp_mov<0x114>(x);
    x += dpp_mov<0x118>(x);
    x += dpp_mov<0x142>(x);
    x += dpp_mov<0x143>(x);
    return __int_as_float(__builtin_amdgcn_readlane(__float_as_int(x), 63));
}
__device__ __forceinline__ float wave_max_bcast(float x) {
    x = fmaxf(x, dpp_mov<0x111>(x));
    x = fmaxf(x, dpp_mov<0x112>(x));
    x = fmaxf(x, dpp_mov<0x114>(x));
    x = fmaxf(x, dpp_mov<0x118>(x));
    x = fmaxf(x, dpp_mov<0x142>(x));
    x = fmaxf(x, dpp_mov<0x143>(x));
    return __int_as_float(__builtin_amdgcn_readlane(__float_as_int(x), 63));
}
__device__ __forceinline__ float rlane(float x, int i) {
    return __int_as_float(__builtin_amdgcn_readlane(__float_as_int(x), i));
}

// Per head: closed-form da/DP/t/Bb; build Ab = diag(da) - DP (x) t; square 11x
// in LDS (stash M = Ab^64 at it==5, transposed, for combine); then solve
// (I - Ab^L)^T Cb = conj(Ct) via in-place transpose + Gauss-Jordan.
extern "C" __global__ void __launch_bounds__(256)
k_precompute(const float* __restrict__ Lre, const float* __restrict__ Lim,
             const float* __restrict__ Pre, const float* __restrict__ Pim,
             const float* __restrict__ Bre, const float* __restrict__ Bim,
             const float* __restrict__ Cmat, const float* __restrict__ logstep,
             float2* __restrict__ wda, float2* __restrict__ wDP,
             float2* __restrict__ wt, float2* __restrict__ wBb,
             float2* __restrict__ wCb, float2* __restrict__ wM) {
    __shared__ __align__(16) float Ar[NN * LDA];
    __shared__ __align__(16) float Ai[NN * LDA];
    __shared__ float2 sda[NN], sDP[NN], st[NN], srhs[NN], sf[NN];

    const int h = blockIdx.x;
    const int tid = threadIdx.x;

    if (tid < NN) {
        const int n = tid;
        float step = expf(logstep[h]);
        float as = 2.0f / step;
        float lr = fminf(Lre[h * NN + n], -1e-4f);
        float li = Lim[h * NN + n];
        float2 a = make_float2(as + lr, li);
        float2 Dn = crecip(make_float2(as - lr, -li));
        float2 P = make_float2(Pre[h * NN + n], Pim[h * NN + n]);
        float2 Bv = make_float2(Bre[h * NN + n], Bim[h * NN + n]);
        float2 cP = make_float2(P.x, -P.y);
        float p2 = P.x * P.x + P.y * P.y;
        float2 rt = cmul(cmul(cP, Dn), Bv);
        float2 e = make_float2(wave_sum_bcast(Dn.x * p2), wave_sum_bcast(Dn.y * p2));
        float2 rv = make_float2(wave_sum_bcast(rt.x), wave_sum_bcast(rt.y));
        float2 cc = crecip(make_float2(1.0f + e.x, e.y));
        float2 da = cmul(Dn, a);
        float2 DPv = cmul(Dn, P);
        float2 tmp = cmul(cc, make_float2(da.x - e.x, da.y - e.y));
        float2 tv = cmul(cP, make_float2(1.0f + tmp.x, tmp.y));
        float2 crv = cmul(cc, rv);
        float2 cd = cmul(crv, DPv);
        float2 db = cmul(Dn, Bv);
        float2 bb = make_float2(2.0f * (db.x - cd.x), 2.0f * (db.y - cd.y));
        sda[n] = da; sDP[n] = DPv; st[n] = tv;
        srhs[n] = make_float2(Cmat[h * NN * 2 + n * 2], -Cmat[h * NN * 2 + n * 2 + 1]);
        wda[h * NN + n] = da; wDP[h * NN + n] = DPv; wt[h * NN + n] = tv;
        wBb[h * NN + n] = bb;
    }
    __syncthreads();

    for (int idx = tid; idx < NN * NN; idx += 256) {
        int i = idx >> 6, j = idx & 63;
        float2 v = cmul(sDP[i], st[j]);
        float mr = -v.x, mi = -v.y;
        if (i == j) { mr += sda[i].x; mi += sda[i].y; }
        Ar[i * LDA + j] = mr; Ai[i * LDA + j] = mi;
    }
    __syncthreads();

    // 11 in-place squarings, 4x4 tile per thread, float4 LDS reads.
    const int i0 = (tid >> 4) << 2, j0 = (tid & 15) << 2;
    for (int it = 0; it < 11; ++it) {
        float acr[4][4] = {}, aci[4][4] = {};
        for (int kk = 0; kk < NN; kk += 4) {
            float a_r[4][4], a_i[4][4], b_r[4][4], b_i[4][4];
            #pragma unroll
            for (int r = 0; r < 4; ++r) {
                *(float4*)a_r[r] = *(const float4*)&Ar[(i0 + r) * LDA + kk];
                *(float4*)a_i[r] = *(const float4*)&Ai[(i0 + r) * LDA + kk];
                *(float4*)b_r[r] = *(const float4*)&Ar[(kk + r) * LDA + j0];
                *(float4*)b_i[r] = *(const float4*)&Ai[(kk + r) * LDA + j0];
            }
            #pragma unroll
            for (int r = 0; r < 4; ++r)
                #pragma unroll
                for (int q = 0; q < 4; ++q) {
                    const float axr = a_r[r][q], axi = a_i[r][q];
                    #pragma unroll
                    for (int c = 0; c < 4; ++c) {
                        acr[r][c] += axr * b_r[q][c] - axi * b_i[q][c];
                        aci[r][c] += axr * b_i[q][c] + axi * b_r[q][c];
                    }
                }
        }
        __syncthreads();   // all reads done before anyone writes
        #pragma unroll
        for (int r = 0; r < 4; ++r) {
            *(float4*)&Ar[(i0 + r) * LDA + j0] = *(float4*)acr[r];
            *(float4*)&Ai[(i0 + r) * LDA + j0] = *(float4*)aci[r];
        }
        __syncthreads();
        if (it == 5) {
            // stash M = Ab^64, transposed: wM[h][j*64+i] = M[i][j] (coalesced)
            for (int idx = tid; idx < NN * NN; idx += 256) {
                int j = idx >> 6, i = idx & 63;
                wM[h * NN * NN + idx] =
                    make_float2(Ar[i * LDA + j], Ai[i * LDA + j]);
            }
        }
    }

    // W = I - Ab^L
    for (int idx = tid; idx < NN * NN; idx += 256) {
        int i = idx >> 6, j = idx & 63;
        float mr = Ar[i * LDA + j], mi = Ai[i * LDA + j];
        Ar[i * LDA + j] = (i == j ? 1.0f : 0.0f) - mr;
        Ai[i * LDA + j] = -mi;
    }
    __syncthreads();
    // in-place transpose (solve W^T Cb = conj(Ct))
    for (int idx = tid; idx < NN * NN; idx += 256) {
        int i = idx >> 6, j = idx & 63;
        if (i < j) {
            float ar = Ar[i * LDA + j], ai = Ai[i * LDA + j];
            Ar[i * LDA + j] = Ar[j * LDA + i]; Ai[i * LDA + j] = Ai[j * LDA + i];
            Ar[j * LDA + i] = ar; Ai[j * LDA + i] = ai;
        }
    }
    __syncthreads();

    // Gauss-Jordan with partial pivoting, 1 RHS
    for (int col = 0; col < NN; ++col) {
        if (tid < 64) {
            const int lane = tid;
            float vr = Ar[lane * LDA + col], vi = Ai[lane * LDA + col];
            float mag = (lane >= col) ? (vr * vr + vi * vi) : 0.0f;
            float vmax = wave_max_bcast(mag);
            unsigned long long ball = __ballot((mag == vmax) && (lane >= col));
            int p = (int)__builtin_ctzll(ball);
            if (p != col) {
                float t1r = Ar[col * LDA + lane], t1i = Ai[col * LDA + lane];
                float t2r = Ar[p * LDA + lane], t2i = Ai[p * LDA + lane];
                Ar[col * LDA + lane] = t2r; Ai[col * LDA + lane] = t2i;
                Ar[p * LDA + lane] = t1r;   Ai[p * LDA + lane] = t1i;
                if (lane == 0) { float2 q = srhs[col]; srhs[col] = srhs[p]; srhs[p] = q; }
            }
        }
        __syncthreads();
        if (tid < 64) {
            const int lane = tid;
            sf[lane] = make_float2(Ar[lane * LDA + col], Ai[lane * LDA + col]);
            float2 ip = crecip(make_float2(Ar[col * LDA + col], Ai[col * LDA + col]));
            float rr = Ar[col * LDA + lane], ri = Ai[col * LDA + lane];
            Ar[col * LDA + lane] = rr * ip.x - ri * ip.y;
            Ai[col * LDA + lane] = rr * ip.y + ri * ip.x;
            if (lane == 0) srhs[col] = cmul(srhs[col], ip);
        }
        __syncthreads();
        {
            const int i = tid >> 2, jb = (tid & 3) * 16;
            if (i != col) {
                float2 f = sf[i];
                #pragma unroll
                for (int jj = 0; jj < 16; ++jj) {
                    int j = jb + jj;
                    float pr = Ar[col * LDA + j], pi = Ai[col * LDA + j];
                    float cr = Ar[i * LDA + j], ci = Ai[i * LDA + j];
                    cr -= f.x * pr - f.y * pi;
                    ci -= f.x * pi + f.y * pr;
                    Ar[i * LDA + j] = cr; Ai[i * LDA + j] = ci;
                }
                if ((tid & 3) == 0) {
                    float2 pr = srhs[col]; float2 cu = srhs[i];
                    cu.x -= f.x * pr.x - f.y * pr.y;
                    cu.y -= f.x * pr.y + f.y * pr.x;
                    srhs[i] = cu;
                }
            }
        }
        __syncthreads();
    }
    if (tid < NN) wCb[h * NN + tid] = srhs[tid];
}

// Krylov vectors per head (one wave): G_m = Ab^m Bb (m=0..63, stored [m][n]),
// V_m = Cb^T Ab^{m+1} (stored [m][n]), K_m = Re(Cb . G_m).
extern "C" __global__ void __launch_bounds__(64)
k_krylov(const float2* __restrict__ wda, const float2* __restrict__ wDP,
         const float2* __restrict__ wt, const float2* __restrict__ wBb,
         const float2* __restrict__ wCb,
         float2* __restrict__ wG, float2* __restrict__ wV,
         float* __restrict__ wK) {
    const int h = blockIdx.x;
    const int lane = threadIdx.x;
    const float2 da = wda[h * NN + lane];
    const float2 DP = wDP[h * NN + lane];
    const float2 tt = wt[h * NN + lane];
    const float2 Cb = wCb[h * NN + lane];
    float Gr = wBb[h * NN + lane].x, Gi = wBb[h * NN + lane].y;
    float vr = Cb.x, vi = Cb.y;

    for (int m = 0; m < TT; ++m) {
        float ch[5];
        ch[0] = Cb.x * Gr - Cb.y * Gi;          // Re(Cb . G_m)
        ch[1] = tt.x * Gr - tt.y * Gi;          // Re(t . G)
        ch[2] = tt.x * Gi + tt.y * Gr;          // Im(t . G)
        ch[3] = vr * DP.x - vi * DP.y;          // Re(v . DP)
        ch[4] = vr * DP.y + vi * DP.x;          // Im(v . DP)
        #pragma unroll
        for (int c = 0; c < 5; ++c) ch[c] += dpp_mov<0x111>(ch[c]);
        #pragma unroll
        for (int c = 0; c < 5; ++c) ch[c] += dpp_mov<0x112>(ch[c]);
        #pragma unroll
        for (int c = 0; c < 5; ++c) ch[c] += dpp_mov<0x114>(ch[c]);
        #pragma unroll
        for (int c = 0; c < 5; ++c) ch[c] += dpp_mov<0x118>(ch[c]);
        #pragma unroll
        for (int c = 0; c < 5; ++c) ch[c] += dpp_mov<0x142>(ch[c]);
        #pragma unroll
        for (int c = 0; c < 5; ++c) ch[c] += dpp_mov<0x143>(ch[c]);
        const float S0 = rlane(ch[0], 63);
        const float S1 = rlane(ch[1], 63);
        const float S2 = rlane(ch[2], 63);
        const float S3 = rlane(ch[3], 63);
        const float S4 = rlane(ch[4], 63);

        wG[h * NN * NN + m * NN + lane] = make_float2(Gr, Gi);
        if (lane == 0) wK[h * NN + m] = S0;
        // G <- Ab G = da o G - DP (t.G)
        float nGr = da.x * Gr - da.y * Gi - (DP.x * S1 - DP.y * S2);
        float nGi = da.x * Gi + da.y * Gr - (DP.x * S2 + DP.y * S1);
        Gr = nGr; Gi = nGi;
        // v <- v Ab = v o da - (v.DP) t
        float nvr = da.x * vr - da.y * vi - (S3 * tt.x - S4 * tt.y);
        float nvi = da.x * vi + da.y * vr - (S3 * tt.y + S4 * tt.x);
        vr = nvr; vi = nvi;
        wV[h * NN * NN + m * NN + lane] = make_float2(vr, vi);  // V_m = Cb^T Ab^{m+1}
    }
}

// Per head: p_c = sum_s G_{63-s} u_{c,s} for all 32 chunks. 256 thr, lane=n.
extern "C" __global__ void __launch_bounds__(256)
k_stage1(const float* __restrict__ u, const float2* __restrict__ wG,
         float2* __restrict__ wP) {
    __shared__ float sGr[NN * NN], sGi[NN * NN];   // [m][n], 32 KB
    __shared__ float su[LL / 1];                   // only CC*TT = 2048 used
    const int h = blockIdx.x;
    const int tid = threadIdx.x;
    for (int idx = tid; idx < NN * NN; idx += 256) {
        float2 g = wG[h * NN * NN + idx];
        sGr[idx] = g.x; sGi[idx] = g.y;
    }
    for (int idx = tid; idx < LL; idx += 256)
        su[idx] = u[idx * HH + h];
    __syncthreads();

    const int wv = tid >> 6, lane = tid & 63;
    float accr[8] = {}, acci[8] = {};
    for (int j = 0; j < TT; ++j) {
        const float gr = sGr[(TT - 1 - j) * NN + lane];
        const float gi = sGi[(TT - 1 - j) * NN + lane];
        #pragma unroll
        for (int q = 0; q < 8; ++q) {
            const float uv = su[((wv * 8 + q) << 6) + j];
            accr[q] += gr * uv; acci[q] += gi * uv;
        }
    }
    #pragma unroll
    for (int q = 0; q < 8; ++q)
        wP[(h * CC + wv * 8 + q) * NN + lane] = make_float2(accr[q], acci[q]);
}

// Sequential chunk-boundary combine: x_start(c) = M x_start(c-1) + p_{c-1}.
extern "C" __global__ void __launch_bounds__(64)
k_combine(const float2* __restrict__ wM, const float2* __restrict__ wP,
          const float* __restrict__ x0_re, const float* __restrict__ x0_im,
          float2* __restrict__ wXs) {
    __shared__ float sMr[NN * NN], sMi[NN * NN];   // [j][i] = M[i][j]
    const int h = blockIdx.x;
    const int lane = threadIdx.x;
    for (int idx = lane; idx < NN * NN; idx += 64) {
        float2 m = wM[h * NN * NN + idx];
        sMr[idx] = m.x; sMi[idx] = m.y;
    }
    __syncthreads();
    float xr = x0_re[lane * HH + h], xi = x0_im[lane * HH + h];
    wXs[(h * CC + 0) * NN + lane] = make_float2(xr, xi);
    for (int c = 1; c < CC; ++c) {
        float nr = 0.0f, ni = 0.0f;
        #pragma unroll 8
        for (int j = 0; j < NN; ++j) {
            const float xjr = rlane(xr, j);
            const float xji = rlane(xi, j);
            const float mr = sMr[j * NN + lane], mi = sMi[j * NN + lane];
            nr += mr * xjr - mi * xji;
            ni += mr * xji + mi * xjr;
        }
        const float2 pe = wP[(h * CC + (c - 1)) * NN + lane];
        xr = nr + pe.x; xi = ni + pe.y;
        wXs[(h * CC + c) * NN + lane] = make_float2(xr, xi);
    }
}

// Per head: y[c][t] = Re(V_t . x_start(c)) + sum_{s<=t} K[t-s] u[c][s] + D u[c][t].
// 256 thr, lane = t, 8 chunks per wave.
extern "C" __global__ void __launch_bounds__(256)
k_stage2(const float* __restrict__ u, const float* __restrict__ Dvec,
         const float2* __restrict__ wV, const float* __restrict__ wK,
         const float2* __restrict__ wXs, float* __restrict__ out) {
    __shared__ float sVr[NN * 65], sVi[NN * 65];   // [n*65+m], padded
    __shared__ float2 sXs[CC * NN];                // 16 KB
    __shared__ float su[LL];                       // 8 KB
    __shared__ float sK[NN];
    const int h = blockIdx.x;
    const int tid = threadIdx.x;
    for (int idx = tid; idx < NN * NN; idx += 256) {
        int m = idx >> 6, n = idx & 63;
        float2 v = wV[h * NN * NN + idx];
        sVr[n * 65 + m] = v.x; sVi[n * 65 + m] = v.y;
    }
    for (int idx = tid; idx < CC * NN; idx += 256)
        sXs[idx] = wXs[h * CC * NN + idx];
    for (int idx = tid; idx < LL; idx += 256)
        su[idx] = u[idx * HH + h];
    if (tid < NN) sK[tid] = wK[h * NN + tid];
    __syncthreads();

    const int wv = tid >> 6, t = tid & 63;
    const float Dh = Dvec[h];
    float acc[8] = {};
    // causal Toeplitz conv with K
    for (int s = 0; s < TT; ++s) {
        const int d = t - s;
        const float kv = (d >= 0) ? sK[d < 0 ? 0 : d] : 0.0f;
        #pragma unroll
        for (int q = 0; q < 8; ++q)
            acc[q] += kv * su[((wv * 8 + q) << 6) + s];
    }
    // boundary term Re(V_t . x_start(c))
    for (int n = 0; n < NN; ++n) {
        const float vvr = sVr[n * 65 + t], vvi = sVi[n * 65 + t];
        #pragma unroll
        for (int q = 0; q < 8; ++q) {
            const float2 xs = sXs[(wv * 8 + q) * NN + n];
            acc[q] += vvr * xs.x - vvi * xs.y;
        }
    }
    #pragma unroll
    for (int q = 0; q < 8; ++q) {
        const int c = wv * 8 + q;
        out[(c * TT + t) * HH + h] = acc[q] + Dh * su[c * TT + t];
    }
}

extern "C" void kernel_launch(void* const* d_in, const int* in_sizes, int n_in,
                              void* d_out, int out_size, void* d_ws, size_t ws_size,
                              hipStream_t stream) {
    const float* u    = (const float*)d_in[0];
    const float* x0re = (const float*)d_in[1];
    const float* x0im = (const float*)d_in[2];
    const float* Lre  = (const float*)d_in[3];
    const float* Lim  = (const float*)d_in[4];
    const float* Pre  = (const float*)d_in[5];
    const float* Pim  = (const float*)d_in[6];
    const float* Bre  = (const float*)d_in[7];
    const float* Bim  = (const float*)d_in[8];
    const float* C    = (const float*)d_in[9];
    const float* Dv   = (const float*)d_in[10];
    const float* lst  = (const float*)d_in[11];

    float2* wda = (float2*)d_ws;
    float2* wDP = wda + HH * NN;
    float2* wt  = wDP + HH * NN;
    float2* wBb = wt + HH * NN;
    float2* wCb = wBb + HH * NN;
    float2* wM  = wCb + HH * NN;              // 16.8 MB
    float2* wG  = wM + HH * NN * NN;          // 16.8 MB
    float2* wV  = wG + HH * NN * NN;          // 16.8 MB
    float2* wP  = wV + HH * NN * NN;          // 8.4 MB
    float2* wXs = wP + HH * CC * NN;          // 8.4 MB
    float*  wK  = (float*)(wXs + HH * CC * NN);
    float* out = (float*)d_out;

    hipLaunchKernelGGL(k_precompute, dim3(HH), dim3(256), 0, stream,
                       Lre, Lim, Pre, Pim, Bre, Bim, C, lst,
                       wda, wDP, wt, wBb, wCb, wM);
    hipLaunchKernelGGL(k_krylov, dim3(HH), dim3(64), 0, stream,
                       wda, wDP, wt, wBb, wCb, wG, wV, wK);
    hipLaunchKernelGGL(k_stage1, dim3(HH), dim3(256), 0, stream,
                       u, wG, wP);
    hipLaunchKernelGGL(k_combine, dim3(HH), dim3(64), 0, stream,
                       wM, wP, x0re, x0im, wXs);
    hipLaunchKernelGGL(k_stage2, dim3(HH), dim3(256), 0, stream,
                       u, Dv, wV, wK, wXs, out);
}